// Round 13
// baseline (114.201 us; speedup 1.0000x reference)
//
#include <hip/hip_runtime.h>
#include <hip/hip_bf16.h>

#define M_TOK 2048
#define KDIM  4096
#define NDIM  4096
#define BM    256
#define BN    256
#define BK    64
#define BUF   32768                // ushorts per buffer: A 16K + B 16K = 64 KB

typedef __bf16 bf16x8 __attribute__((ext_vector_type(8)));
typedef float  f32x4  __attribute__((ext_vector_type(4)));
typedef short  short8 __attribute__((ext_vector_type(8)));

__device__ __forceinline__ ushort f2bf(float f) {
    union { float f; unsigned u; } v; v.f = f;
    unsigned r = (v.u + 0x7fffu + ((v.u >> 16) & 1u)) >> 16;
    return (ushort)r;
}

__device__ __forceinline__ void gload16(const ushort* g, ushort* l) {
    __builtin_amdgcn_global_load_lds(
        (const __attribute__((address_space(1))) void*)g,
        (__attribute__((address_space(3))) void*)l, 16, 0, 0);
}

// ---------------- kernel 1: cast x -> bf16  AND  build W3 row-major ----------------
__global__ __launch_bounds__(256) void k_prep(const float* __restrict__ x,
                                              ushort* __restrict__ xb,
                                              const float* __restrict__ g0,
                                              const float* __restrict__ g1,
                                              const float* __restrict__ alpha,
                                              const float* __restrict__ pds,
                                              const int* __restrict__ iperm,
                                              const int* __restrict__ oinv,
                                              ushort* __restrict__ W3) {
    __shared__ float  G0s[1024];   // [j0][r]
    __shared__ float  G1s[1024];   // [r][j1]
    __shared__ ushort rowb[4096];
    const int b = blockIdx.x;
    if (b < 4096) {
        const int i = (b * 256 + threadIdx.x) * 8;
        float4 a = *reinterpret_cast<const float4*>(x + i);
        float4 c = *reinterpret_cast<const float4*>(x + i + 4);
        short8 o;
        o[0] = (short)f2bf(a.x); o[1] = (short)f2bf(a.y);
        o[2] = (short)f2bf(a.z); o[3] = (short)f2bf(a.w);
        o[4] = (short)f2bf(c.x); o[5] = (short)f2bf(c.y);
        o[6] = (short)f2bf(c.z); o[7] = (short)f2bf(c.w);
        *reinterpret_cast<short8*>(xb + i) = o;
        return;
    }
    const int o  = b - 4096;
    const int op = oinv[o];
    const int i0 = op >> 6, i1 = op & 63;
    const float sc = alpha[0] * pds[op];

    for (int idx = threadIdx.x; idx < 1024; idx += 256) {
        G0s[idx] = g0[i0 * 1024 + idx];
        G1s[idx] = g1[(idx >> 6) * 4096 + i1 * 64 + (idx & 63)];
    }
    __syncthreads();

    float g1c[16];
#pragma unroll
    for (int r = 0; r < 16; ++r) g1c[r] = G1s[r * 64 + (threadIdx.x & 63)];

#pragma unroll 4
    for (int s = 0; s < 16; ++s) {
        const int jp = threadIdx.x + s * 256;
        const int j0 = jp >> 6;
        const float4 q0 = *reinterpret_cast<const float4*>(&G0s[j0 * 16]);
        const float4 q1 = *reinterpret_cast<const float4*>(&G0s[j0 * 16 + 4]);
        const float4 q2 = *reinterpret_cast<const float4*>(&G0s[j0 * 16 + 8]);
        const float4 q3 = *reinterpret_cast<const float4*>(&G0s[j0 * 16 + 12]);
        float v = 0.f;
        v = fmaf(q0.x, g1c[0], v);  v = fmaf(q0.y, g1c[1], v);
        v = fmaf(q0.z, g1c[2], v);  v = fmaf(q0.w, g1c[3], v);
        v = fmaf(q1.x, g1c[4], v);  v = fmaf(q1.y, g1c[5], v);
        v = fmaf(q1.z, g1c[6], v);  v = fmaf(q1.w, g1c[7], v);
        v = fmaf(q2.x, g1c[8], v);  v = fmaf(q2.y, g1c[9], v);
        v = fmaf(q2.z, g1c[10], v); v = fmaf(q2.w, g1c[11], v);
        v = fmaf(q3.x, g1c[12], v); v = fmaf(q3.y, g1c[13], v);
        v = fmaf(q3.z, g1c[14], v); v = fmaf(q3.w, g1c[15], v);
        rowb[iperm[jp]] = f2bf(v * sc);
    }
    __syncthreads();
#pragma unroll
    for (int u = 0; u < 2; ++u) {
        const int t = threadIdx.x + u * 256;
        *reinterpret_cast<short8*>(W3 + (size_t)o * 4096 + t * 8) =
            *reinterpret_cast<const short8*>(rowb + t * 8);
    }
}

// ---------------- kernel 2: C = A @ B^T (+ bias)  [m201 geometry, split-K] -------
// block 256x256, BK=64, 512 thr = 8 waves (2M x 4N), wave tile 128x64.
// 2-buffer LDS (128KB), half-tile staging (1 unit = 2 gloads per phase),
// 4 quadrant-phases/tile x 16 MFMA, vmcnt(4) once/tile, zero-conflict swizzle.
// ksplit=2: bid>>7 selects K-half; kz0 -> out(+bias), kz1 -> P1 partial.
__global__ __launch_bounds__(512, 1)
void k_gemm(const ushort* __restrict__ A, const ushort* __restrict__ Bw,
            const float* __restrict__ bias, float* __restrict__ Cout,
            float* __restrict__ P1, int ksplit) {
    __shared__ __align__(16) ushort lds[2 * BUF];   // 128 KB
    const int tid  = threadIdx.x;
    const int lane = tid & 63;
    const int w    = tid >> 6;   // 0..7
    const int wm   = w >> 2;     // 0..1
    const int wn   = w & 3;      // 0..3

    int half, r;
    if (ksplit == 2) { half = blockIdx.x >> 7; r = blockIdx.x & 127; }
    else             { half = 0;               r = blockIdx.x; }
    const int ntk   = (ksplit == 2) ? 32 : 64;
    const int kbase = half * 2048;
    // XCD map over 128 blocks: 8x16 grid, XCD owns 2 bx columns x all by
    const int xcd = r & 7, li = r >> 3;       // li 0..15
    const int by = li >> 1;                   // 0..7
    const int bx = xcd * 2 + (li & 1);        // 0..15
    const long brow = (long)by * BM, bcol = (long)bx * BN;

    float* const dst = half ? P1 : Cout;

    // ---- staging: unit u = {0:A rows 0-127, 1:A 128-255, 2:B 0-127, 3:B 128-255}
    // 64-row sweeps: thread t -> row t>>3, LDS slot t&7, global slot ^(row&7)
    const int rowt = tid >> 3;
    const int scol = ((tid & 7) ^ (rowt & 7)) << 3;
    const ushort* gA0 = A  + (size_t)(brow + rowt) * KDIM + scol;
    const ushort* gB0 = Bw + (size_t)(bcol + rowt) * KDIM + scol;
    const int wub = (tid & ~63) * 8;

    auto stage = [&](int bufo, int g, int unit) {
        const int kt = kbase + g * BK;
        const ushort* gs = (unit < 2 ? gA0 + (size_t)(unit * 128) * KDIM
                                     : gB0 + (size_t)((unit - 2) * 128) * KDIM) + kt;
        ushort* d = (ushort*)lds + bufo + unit * 8192 + wub;
        gload16(gs, d);
        gload16(gs + (size_t)64 * KDIM, d + 4096);
    };

    // ---- fragment reads (proven zero-conflict, 128B rows)
    const int lr = lane & 15;
    int colswz[2];
#pragma unroll
    for (int kk = 0; kk < 2; ++kk)
        colswz[kk] = ((kk * 4 + (lane >> 4)) ^ (lane & 7)) * 8;
    const int rA = (wm * 128 + lr) * 64;            // + m*1024
    const int rB = 16384 + (wn * 64 + lr) * 64;     // + n*1024

    f32x4  acc[8][4] = {};
    bf16x8 af[4][2], bf0[2][2], bf1[2][2];

#define BARRIER do { asm volatile("" ::: "memory"); \
                     __builtin_amdgcn_s_barrier();  \
                     asm volatile("" ::: "memory"); } while (0)
#define LGKM0 asm volatile("s_waitcnt lgkmcnt(0)" ::: "memory")
#define VM4   asm volatile("s_waitcnt vmcnt(4)" ::: "memory")
#define VM0   asm volatile("s_waitcnt vmcnt(0)" ::: "memory")

    // prologue: tile0 full + tile1 {A0,B1}; wait tile0 (4 newest remain)
    stage(0, 0, 0); stage(0, 0, 1); stage(0, 0, 2); stage(0, 0, 3);
    stage(BUF, 1, 0); stage(BUF, 1, 3);
    VM4;
    BARRIER;

    for (int g = 0; g < ntk; ++g) {
        const int bufo = (g & 1) * BUF;
        const int nxto = bufo ^ BUF;
        // ---- ph1: Q00  (reads A0 + B0; stage (g+1,A1)->nxt)
#pragma unroll
        for (int m = 0; m < 4; ++m)
#pragma unroll
            for (int kk = 0; kk < 2; ++kk)
                af[m][kk] = *reinterpret_cast<const bf16x8*>(
                    lds + bufo + rA + m * 1024 + colswz[kk]);
#pragma unroll
        for (int n = 0; n < 2; ++n)
#pragma unroll
            for (int kk = 0; kk < 2; ++kk)
                bf0[n][kk] = *reinterpret_cast<const bf16x8*>(
                    lds + bufo + rB + n * 1024 + colswz[kk]);
        if (g + 1 < ntk) stage(nxto, g + 1, 1);
        BARRIER; LGKM0;
        __builtin_amdgcn_s_setprio(1);
#pragma unroll
        for (int kk = 0; kk < 2; ++kk)
#pragma unroll
            for (int m = 0; m < 4; ++m)
#pragma unroll
                for (int n = 0; n < 2; ++n)
                    acc[m][n] = __builtin_amdgcn_mfma_f32_16x16x32_bf16(
                        af[m][kk], bf0[n][kk], acc[m][n], 0, 0, 0);
        __builtin_amdgcn_s_setprio(0);
        BARRIER;
        // ---- ph2: Q01  (reads B1; stage (g+1,B0)->nxt)
#pragma unroll
        for (int n = 0; n < 2; ++n)
#pragma unroll
            for (int kk = 0; kk < 2; ++kk)
                bf1[n][kk] = *reinterpret_cast<const bf16x8*>(
                    lds + bufo + rB + (n + 2) * 1024 + colswz[kk]);
        if (g + 1 < ntk) stage(nxto, g + 1, 2);
        BARRIER; LGKM0;
        __builtin_amdgcn_s_setprio(1);
#pragma unroll
        for (int kk = 0; kk < 2; ++kk)
#pragma unroll
            for (int m = 0; m < 4; ++m)
#pragma unroll
                for (int n = 0; n < 2; ++n)
                    acc[m][n + 2] = __builtin_amdgcn_mfma_f32_16x16x32_bf16(
                        af[m][kk], bf1[n][kk], acc[m][n + 2], 0, 0, 0);
        __builtin_amdgcn_s_setprio(0);
        BARRIER;
        // ---- ph3: Q11  (reads A1; stage (g+2,A0)->bufo, A0 freed at ph2 end)
#pragma unroll
        for (int m = 0; m < 4; ++m)
#pragma unroll
            for (int kk = 0; kk < 2; ++kk)
                af[m][kk] = *reinterpret_cast<const bf16x8*>(
                    lds + bufo + rA + (m + 4) * 1024 + colswz[kk]);
        if (g + 2 < ntk) stage(bufo, g + 2, 0);
        BARRIER; LGKM0;
        __builtin_amdgcn_s_setprio(1);
#pragma unroll
        for (int kk = 0; kk < 2; ++kk)
#pragma unroll
            for (int m = 0; m < 4; ++m)
#pragma unroll
                for (int n = 0; n < 2; ++n)
                    acc[m + 4][n + 2] = __builtin_amdgcn_mfma_f32_16x16x32_bf16(
                        af[m][kk], bf1[n][kk], acc[m + 4][n + 2], 0, 0, 0);
        __builtin_amdgcn_s_setprio(0);
        BARRIER;
        // ---- ph4: Q10  (no reads; stage (g+2,B1)->bufo, B1 freed at ph3 end)
        if (g + 2 < ntk) stage(bufo, g + 2, 3);
        __builtin_amdgcn_s_setprio(1);
#pragma unroll
        for (int kk = 0; kk < 2; ++kk)
#pragma unroll
            for (int m = 0; m < 4; ++m)
#pragma unroll
                for (int n = 0; n < 2; ++n)
                    acc[m + 4][n] = __builtin_amdgcn_mfma_f32_16x16x32_bf16(
                        af[m][kk], bf0[n][kk], acc[m + 4][n], 0, 0, 0);
        __builtin_amdgcn_s_setprio(0);
        if (g + 2 < ntk)      VM4;   // (g+1) units landed; (g+2,A0/B1) in flight
        else if (g + 1 < ntk) VM0;   // drain last tile's units
        BARRIER;
    }
#undef BARRIER
#undef LGKM0
#undef VM4
#undef VM0

    // ---- epilogue: col = lane&15, row = (lane>>4)*4 + v
    const int orow = (lane >> 4) * 4;
    float bv[4];
#pragma unroll
    for (int n = 0; n < 4; ++n)
        bv[n] = half ? 0.f : bias[bcol + wn * 64 + n * 16 + lr];
#pragma unroll
    for (int m = 0; m < 8; ++m) {
#pragma unroll
        for (int v = 0; v < 4; ++v) {
            const long grow = brow + wm * 128 + m * 16 + orow + v;
            float* cp = dst + grow * NDIM + bcol + wn * 64 + lr;
#pragma unroll
            for (int n = 0; n < 4; ++n)
                cp[n * 16] = acc[m][n][v] + bv[n];
        }
    }
}

// ---------------- kernel 3: out += P1 ----------------
__global__ __launch_bounds__(256) void k_red(float* __restrict__ out,
                                             const float* __restrict__ p1) {
    const int i = (blockIdx.x * 256 + threadIdx.x) * 4;
    float4 a = *reinterpret_cast<const float4*>(out + i);
    const float4 b = *reinterpret_cast<const float4*>(p1 + i);
    a.x += b.x; a.y += b.y; a.z += b.z; a.w += b.w;
    *reinterpret_cast<float4*>(out + i) = a;
}

extern "C" void kernel_launch(void* const* d_in, const int* in_sizes, int n_in,
                              void* d_out, int out_size, void* d_ws, size_t ws_size,
                              hipStream_t stream) {
    const float* x     = (const float*)d_in[0];
    const float* g0    = (const float*)d_in[1];
    const float* g1    = (const float*)d_in[2];
    const float* alpha = (const float*)d_in[3];
    const float* pds   = (const float*)d_in[4];
    const float* bias  = (const float*)d_in[5];
    const int*   iperm = (const int*)d_in[6];
    const int*   oinv  = (const int*)d_in[7];
    float* out = (float*)d_out;

    ushort* W3 = (ushort*)d_ws;                         // 32MB bf16 W3
    ushort* Xb = (ushort*)d_ws + (size_t)NDIM * KDIM;   // 16MB bf16 A
    const bool split = ws_size >= (size_t)80 * 1024 * 1024;
    float* P1 = split ? (float*)((char*)d_ws + (size_t)48 * 1024 * 1024)
                      : (float*)d_ws;                   // unused when !split

    hipLaunchKernelGGL(k_prep, dim3(8192), dim3(256), 0, stream,
                       x, Xb, g0, g1, alpha, pds, iperm, oinv, W3);
    if (split) {
        hipLaunchKernelGGL(k_gemm, dim3(256), dim3(512), 0, stream,
                           Xb, W3, bias, out, P1, 2);
        hipLaunchKernelGGL(k_red, dim3((M_TOK * NDIM) / (256 * 4)), dim3(256), 0,
                           stream, out, P1);
    } else {
        hipLaunchKernelGGL(k_gemm, dim3(128), dim3(512), 0, stream,
                           Xb, W3, bias, out, P1, 1);
    }
}